// Round 16
// baseline (219.955 us; speedup 1.0000x reference)
//
#include <hip/hip_runtime.h>
#include <hip/hip_bf16.h>
#include <stdint.h>

typedef __attribute__((ext_vector_type(16))) float f32x16;
typedef __attribute__((ext_vector_type(4)))  float f32x4;
typedef __attribute__((ext_vector_type(4), aligned(4))) float f32x4u;  // 4B-aligned vec load
typedef __attribute__((ext_vector_type(8)))  __bf16 bf16x8;

#define CIN 64
#define HW 96
#define PW 98
#define OCH 128
#define NF 54
#define PCH (PW*PW)            // 9604
#define PIMG (CIN*PCH)         // 614656
#define PAD_FLOATS (8*PIMG)    // 4917248
#define PAD_BYTES ((size_t)PAD_FLOATS*4)
#define CHB 16384              // bytes per channel weight slab (128 oc x 64 k x 2B)
#define WB_BYTES ((size_t)CIN*CHB)   // 1 MiB

// ---------- pad x: [8][64][96][96] -> [8][64][98][98] zero-rimmed
__global__ __launch_bounds__(256) void prep_pad(const float* __restrict__ x,
                                                float* __restrict__ xp) {
    int idx = blockIdx.x*256 + threadIdx.x;    // grid sized exactly
    int pw_ = idx % PW;
    int t   = idx / PW;
    int ph  = t % PW;
    int ic  = t / PW;
    int h = ph - 1, w = pw_ - 1;
    float v = (((unsigned)h < HW) & ((unsigned)w < HW))
            ? x[(size_t)ic*(HW*HW) + h*HW + w] : 0.f;
    xp[idx] = v;
}

// ---------- weight prep: fp32 [oc 128][c 64][54] -> bf16 fragment-native
// elem index = ((c*4 + kc)*2 + hi)*1024 + oc*8 + i   (k = kc*16 + hi*8 + i)
__global__ __launch_bounds__(256) void prep_w(const float* __restrict__ w,
                                              __bf16* __restrict__ wb) {
    int idx = blockIdx.x * 256 + threadIdx.x;   // 262144
    int j  = idx & 31;
    int oc = (idx >> 5) & 127;
    int c  = idx >> 12;
    int k  = 2 * j;
    int kc = k >> 4, hi = (k >> 3) & 1, i = k & 7;
    float v0 = (k     < NF) ? w[(oc*CIN + c)*NF + k    ] : 0.f;
    float v1 = (k + 1 < NF) ? w[(oc*CIN + c)*NF + k + 1] : 0.f;
    size_t off = ((size_t)(c*8 + kc*2 + hi))*1024 + oc*8 + i;
    union { __bf16 b[2]; uint32_t u; } pk;
    pk.b[0] = (__bf16)v0; pk.b[1] = (__bf16)v1;
    *(uint32_t*)((char*)wb + off*2) = pk.u;
}

// cross-product pair tables (PM_cross order)
__device__ __forceinline__ constexpr int PIc(int k) {
    constexpr int t[36] = {0,1,2,3,4,5,6,7, 0,1,2,3,4,5,6, 0,1,2,3,4,5,
                           0,1,2,3,4, 0,1,2,3, 0,1,2, 0,1, 0};
    return t[k];
}
__device__ __forceinline__ constexpr int PJc(int k) {
    constexpr int t[36] = {1,2,3,4,5,6,7,8, 2,3,4,5,6,7,8, 3,4,5,6,7,8,
                           4,5,6,7,8, 5,6,7,8, 6,7,8, 7,8, 8};
    return t[k];
}

// runtime k, fully constant-folds under #pragma unroll
__device__ __forceinline__ float featv(int k, const float* q) {
    return (k < 9)  ? q[k]
         : (k < 18) ? q[k-9] * q[k-9]
         : (k < 54) ? q[PIc(k-18)] * q[PJc(k-18)]
         : 0.f;
}

// build lane's B-fragment for K-group KC. Pack via the HW packed-convert
// v_cvt_pk_bf16_f32 (one VALU op per feature PAIR; T12 recipe - no builtin
// on gfx950). D[15:0]=bf16(S0), D[31:16]=bf16(S1), RNE - matches union code.
template<int KC>
__device__ __forceinline__ bf16x8 mkfrag(const float* q, int hi) {
    uint32_t P[8];
#pragma unroll
    for (int j = 0; j < 8; j++) {
        float f0 = featv(KC*16 + 2*j,     q);
        float f1 = featv(KC*16 + 2*j + 1, q);
        uint32_t r;
        asm("v_cvt_pk_bf16_f32 %0, %1, %2" : "=v"(r) : "v"(f0), "v"(f1));
        P[j] = r;
    }
    union { uint32_t u[4]; bf16x8 v; } t;
#pragma unroll
    for (int j = 0; j < 4; j++) t.u[j] = hi ? P[4+j] : P[j];
    return t.v;
}

__device__ __forceinline__ void gload_lds16(const void* g, void* l) {
    __builtin_amdgcn_global_load_lds(
        (const __attribute__((address_space(1))) void*)g,
        (__attribute__((address_space(3))) void*)l, 16, 0, 0);
}

// one K-group: 4 A ds_reads + B build + 4 MFMA. KC/WSEL compile-time (rule #20).
template<int KC, int WSEL>
__device__ __forceinline__ void kcstep(const char* bufc, const float* q, int hi,
                                       int l31, f32x16 (&acc)[4]) {
    bf16x8 A[4];
#pragma unroll
    for (int os = 0; os < 4; os++)
        A[os] = *(const bf16x8*)(bufc + (KC*2 + hi)*2048 + (((os^WSEL)*32) + l31)*16);
    bf16x8 tb = mkfrag<KC>(q, hi);
#pragma unroll
    for (int os = 0; os < 4; os++)
        acc[os] = __builtin_amdgcn_mfma_f32_32x32x16_bf16(A[os], tb, acc[os], 0, 0, 0);
}

// ---------- main (r13 base + cvt_pk pack + R double-buffer prefetch).
// Block = 512 thr = 8 waves = 4 pos-groups x 2 channel-halves. Wave = 32 pos
// x 128 oc x 32 channels (half h: channels h*32..+31). Per-half LDS slab
// double-buffer (64 KB/block, 2 blocks/CU -> 4 waves/SIMD at <=128 regs).
// R window for channel t+1 prefetched during step t (r10 pattern): in-order
// vmcnt means the q-build waits at vmcnt(outstanding), never a full drain.
// XOR ownership: local acc block os = global oc block (os ^ (h<<1)); K-combine
// via LDS with partner wave (wv^4). All acc subscripts compile-time (rule #20).
// mfma_f32_32x32x16_bf16: A/B lane: row/col = lane&31, k = (lane>>5)*8+i;
// D: col = lane&31, row = (reg&3) + 8*(reg>>2) + 4*(lane>>5).
__global__ __launch_bounds__(512, 4) void socg_ks(const float* __restrict__ xp,
                                                  const __bf16* __restrict__ wb,
                                                  float* __restrict__ out) {
    __shared__ __align__(16) char sw[2][2][CHB];   // [half][dbuf][slab] = 64 KiB

    const int tid  = threadIdx.x;
    const int lane = tid & 63;
    const int wv   = tid >> 6;      // 0..7
    const int g    = wv & 3;        // pos-group
    const int h    = wv >> 2;       // channel-half (wave-uniform)
    const int hi   = lane >> 5;
    const int l31  = lane & 31;
    const int wsel = h << 1;        // XOR remap of oc blocks per half

    const int bid  = blockIdx.x;    // 576 = 8 imgs * 72 tiles
    const int bimg = bid & 7;       // XCD k -> image k (L2 locality)
    const int rem  = bid >> 3;      // 0..71
    const int h0   = (rem / 6) * 8; // block tile: 8 rows x 16 cols
    const int w0   = (rem % 6) * 16;

    const int r0 = h0 + g*2 + (l31 >> 4);
    const int c0 = w0 + (l31 & 15);

    const char* xbase = (const char*)(xp + (size_t)bimg*PIMG + (size_t)(h*32)*PCH);
    const int voff0 = (r0*PW + c0) * 4;

    f32x16 acc[4];
#pragma unroll
    for (int os = 0; os < 4; os++)
#pragma unroll
        for (int r = 0; r < 16; r++) acc[os][r] = 0.f;

    // prologue: stage step-0 slab for my half + load channel-0 window
    {
        const char* wsrc = (const char*)wb + (size_t)(h*32)*CHB;
#pragma unroll
        for (int i = 0; i < 4; i++) {
            const int m = i*4 + g;
            gload_lds16(wsrc + m*1024 + lane*16, &sw[h][0][0] + m*1024);
        }
    }
    f32x4 R0[3], R1[3];
#pragma unroll
    for (int j = 0; j < 3; j++)
        R0[j] = (f32x4)*(const f32x4u*)(xbase + voff0 + j*(PW*4));
    __syncthreads();

    auto body = [&](f32x4 (&Rc)[3], f32x4 (&Rn)[3], int t) {
        char* bufc = &sw[h][t & 1][0];
        // 1) prefetch NEXT channel's window + stage NEXT slab (both land later;
        //    current q-build only waits for Rc, which is already resident)
        if (t + 1 < 32) {
            const char* xn = xbase + (size_t)(t + 1)*(PCH*4);
#pragma unroll
            for (int j = 0; j < 3; j++)
                Rn[j] = (f32x4)*(const f32x4u*)(xn + voff0 + j*(PW*4));
            const char* wsrc = (const char*)wb + (size_t)(h*32 + t + 1)*CHB;
            char* bufn = &sw[h][(t + 1) & 1][0];
#pragma unroll
            for (int i = 0; i < 4; i++) {
                const int m = i*4 + g;
                gload_lds16(wsrc + m*1024 + lane*16, bufn + m*1024);
            }
        }
        // 2) window from registers (loaded last step)
        float q[9];
#pragma unroll
        for (int j = 0; j < 3; j++) {
            q[j*3 + 0] = Rc[j][0]; q[j*3 + 1] = Rc[j][1]; q[j*3 + 2] = Rc[j][2];
        }
        // 3) 4 K-groups: ds_read A + cvt_pk build + MFMA
        if (h == 0) {
            kcstep<0, 0>(bufc, q, hi, l31, acc);
            kcstep<1, 0>(bufc, q, hi, l31, acc);
            kcstep<2, 0>(bufc, q, hi, l31, acc);
            kcstep<3, 0>(bufc, q, hi, l31, acc);
        } else {
            kcstep<0, 2>(bufc, q, hi, l31, acc);
            kcstep<1, 2>(bufc, q, hi, l31, acc);
            kcstep<2, 2>(bufc, q, hi, l31, acc);
            kcstep<3, 2>(bufc, q, hi, l31, acc);
        }
        // 4) barrier: my slab reads done + stage(t+1) landed
        __syncthreads();
    };

#pragma unroll 1
    for (int t2 = 0; t2 < 32; t2 += 2) {
        body(R0, R1, t2);
        body(R1, R0, t2 + 1);
    }

    // ---- K-combine with partner wave (wv^4). Each wave STORES local acc[2],
    // acc[3] (partner's global oc blocks) and ADDS partner's contribution into
    // acc[0],acc[1]. All indices compile-time; lane*16 layout -> conflict-free.
    {
        char* lred = &sw[0][0][0];     // reuse 64 KB slab space
        char* my = lred + wv*8192;
#pragma unroll
        for (int g2 = 0; g2 < 8; g2++) {
            f32x4 v;
            v[0] = acc[2 + (g2>>2)][(g2&3)*4 + 0];
            v[1] = acc[2 + (g2>>2)][(g2&3)*4 + 1];
            v[2] = acc[2 + (g2>>2)][(g2&3)*4 + 2];
            v[3] = acc[2 + (g2>>2)][(g2&3)*4 + 3];
            *(f32x4*)(my + g2*1024 + lane*16) = v;
        }
        __syncthreads();
        const char* ot = lred + (wv ^ 4)*8192;
#pragma unroll
        for (int g2 = 0; g2 < 8; g2++) {
            f32x4 v = *(const f32x4*)(ot + g2*1024 + lane*16);
            acc[g2>>2][(g2&3)*4 + 0] += v[0];
            acc[g2>>2][(g2&3)*4 + 1] += v[1];
            acc[g2>>2][(g2&3)*4 + 2] += v[2];
            acc[g2>>2][(g2&3)*4 + 3] += v[3];
        }
    }

    // epilogue: write local acc[0],acc[1] -> global oc blocks (osl ^ wsel)
    const size_t obase = (size_t)bimg*OCH*HW*HW + (size_t)r0*HW + c0;
#pragma unroll
    for (int osl = 0; osl < 2; osl++) {
        const int gblk = osl ^ wsel;
#pragma unroll
        for (int r = 0; r < 16; r++) {
            const int oc = gblk*32 + (r & 3) + 8*(r >> 2) + 4*hi;
            out[obase + (size_t)oc*(HW*HW)] = acc[osl][r];
        }
    }
}

// ---------- fallback (no pad buffer): register-path kernel
__global__ __launch_bounds__(64, 3) void socg_fb(const float* __restrict__ x,
                                                 const __bf16* __restrict__ wb,
                                                 float* __restrict__ out) {
    const int lane = threadIdx.x;
    const int hi   = lane >> 5;
    const int l31  = lane & 31;

    const int bid  = blockIdx.x;
    const int bimg = bid / 288;
    const int rem  = bid - bimg * 288;
    const int h0   = (rem / 6) * 2;
    const int w0   = (rem % 6) * 16;

    const int hA = h0 + (l31 >> 4);
    const int wA = w0 + (l31 & 15);

    int   off[9];
    float msk[9];
#pragma unroll
    for (int rr = 0; rr < 3; rr++)
#pragma unroll
        for (int cc = 0; cc < 3; cc++) {
            int hh = hA - 1 + rr, ww = wA - 1 + cc;
            bool ok = ((unsigned)hh < HW) && ((unsigned)ww < HW);
            int hc = hh < 0 ? 0 : (hh > HW-1 ? HW-1 : hh);
            int wc = ww < 0 ? 0 : (ww > HW-1 ? HW-1 : ww);
            off[rr*3 + cc] = hc * HW + wc;
            msk[rr*3 + cc] = ok ? 1.f : 0.f;
        }

    const float* xb = x + (size_t)bimg * CIN * HW * HW;

    f32x16 acc[4];
#pragma unroll
    for (int os = 0; os < 4; os++)
#pragma unroll
        for (int r = 0; r < 16; r++) acc[os][r] = 0.f;

    float rA[9], rB[9];
#pragma unroll
    for (int i = 0; i < 9; i++) rA[i] = xb[off[i]];

    auto loadA = [&](bf16x8 (&A)[4], const __bf16* wc_, int kc) {
#pragma unroll
        for (int os = 0; os < 4; os++)
            A[os] = *(const bf16x8*)(wc_ + (kc*2 + hi)*1024 + (os*32 + l31)*8);
    };

    auto body = [&](float (&rc)[9], float (&rn)[9], int c) {
        const __bf16* wc_ = wb + (size_t)c * 8192;
        bf16x8 A0[4], A1[4], A2[4], A3[4];
        loadA(A0, wc_, 0);
        loadA(A1, wc_, 1);
        loadA(A2, wc_, 2);
        loadA(A3, wc_, 3);
        if (c + 1 < CIN) {
            const float* xn = xb + (size_t)(c + 1) * HW * HW;
#pragma unroll
            for (int i = 0; i < 9; i++) rn[i] = xn[off[i]];
        }
        float q[9];
#pragma unroll
        for (int i = 0; i < 9; i++) q[i] = rc[i] * msk[i];

        {
            bf16x8 tb = mkfrag<0>(q, hi);
#pragma unroll
            for (int os = 0; os < 4; os++)
                acc[os] = __builtin_amdgcn_mfma_f32_32x32x16_bf16(A0[os], tb, acc[os], 0, 0, 0);
        }
        {
            bf16x8 tb = mkfrag<1>(q, hi);
#pragma unroll
            for (int os = 0; os < 4; os++)
                acc[os] = __builtin_amdgcn_mfma_f32_32x32x16_bf16(A1[os], tb, acc[os], 0, 0, 0);
        }
        {
            bf16x8 tb = mkfrag<2>(q, hi);
#pragma unroll
            for (int os = 0; os < 4; os++)
                acc[os] = __builtin_amdgcn_mfma_f32_32x32x16_bf16(A2[os], tb, acc[os], 0, 0, 0);
        }
        {
            bf16x8 tb = mkfrag<3>(q, hi);
#pragma unroll
            for (int os = 0; os < 4; os++)
                acc[os] = __builtin_amdgcn_mfma_f32_32x32x16_bf16(A3[os], tb, acc[os], 0, 0, 0);
        }
    };

#pragma unroll 1
    for (int c2 = 0; c2 < CIN; c2 += 2) {
        body(rA, rB, c2);
        body(rB, rA, c2 + 1);
    }

#pragma unroll
    for (int os = 0; os < 4; os++)
#pragma unroll
        for (int r = 0; r < 16; r++) {
            int oc = os*32 + (r & 3) + 8*(r >> 2) + 4*hi;
            out[(((size_t)bimg*OCH + oc)*HW + hA)*HW + wA] = acc[os][r];
        }
}

extern "C" void kernel_launch(void* const* d_in, const int* in_sizes, int n_in,
                              void* d_out, int out_size, void* d_ws, size_t ws_size,
                              hipStream_t stream) {
    const float* x = (const float*)d_in[0];
    const float* w = (const float*)d_in[1];
    float* out = (float*)d_out;
    if (ws_size >= PAD_BYTES + WB_BYTES) {
        float* xpad = (float*)d_ws;
        __bf16* wbf = (__bf16*)((char*)d_ws + PAD_BYTES);
        hipLaunchKernelGGL(prep_pad, dim3(PAD_FLOATS/256), dim3(256), 0, stream, x, xpad);
        hipLaunchKernelGGL(prep_w, dim3(1024), dim3(256), 0, stream, w, wbf);
        hipLaunchKernelGGL(socg_ks, dim3(576), dim3(512), 0, stream, xpad, wbf, out);
    } else {
        __bf16* wbf = (__bf16*)d_ws;
        hipLaunchKernelGGL(prep_w, dim3(1024), dim3(256), 0, stream, w, wbf);
        hipLaunchKernelGGL(socg_fb, dim3(2304), dim3(64), 0, stream, x, wbf, out);
    }
}

// Round 17
// 135.683 us; speedup vs baseline: 1.6211x; 1.6211x over previous
//
#include <hip/hip_runtime.h>
#include <hip/hip_bf16.h>
#include <stdint.h>

typedef __attribute__((ext_vector_type(16))) float f32x16;
typedef __attribute__((ext_vector_type(4)))  float f32x4;
typedef __attribute__((ext_vector_type(8)))  __bf16 bf16x8;
typedef _Float16 h2    __attribute__((ext_vector_type(2)));   // packed fp16 pair (1 VGPR)
typedef _Float16 f16x8 __attribute__((ext_vector_type(8)));   // MFMA A/B operand

#define CIN 64
#define HW 96
#define OCH 128
#define NF 54
#define PW2 98
#define CSLAB (PW2*PW2)                  // 9604 elems per channel (fp16 padded)
#define COPYE ((size_t)8*CIN*CSLAB)      // 4,917,248 elems per parity copy
#define COPYB (COPYE*2)                  // bytes per copy
#define XH_BYTES (COPYB*2)               // 19,668,992 (== old PAD_BYTES)
#define CHB 16384                        // per-channel weight slab bytes (128oc x 64k x 2B)
#define WB_BYTES ((size_t)CIN*CHB)       // 1 MiB

// ---------- input prep: fp32 [8][64][96][96] -> TWO fp16 padded copies
// copy s: buffer col cb <-> global col cb-1-s; row rb <-> global row rb-1.
// Lane with position col c0 uses copy s=c0&1 so its window byte addr is 4B-aligned.
__global__ __launch_bounds__(256) void prep_pad2(const float* __restrict__ x,
                                                 _Float16* __restrict__ xh) {
    size_t idx = (size_t)blockIdx.x*256 + threadIdx.x;   // 9,834,496 total
    int s  = (int)(idx / COPYE);
    int r1 = (int)(idx - (size_t)s*COPYE);
    int ic = r1 / CSLAB;
    int r2 = r1 - ic*CSLAB;
    int rb = r2 / PW2, cb = r2 - rb*PW2;
    int gr = rb - 1, gc = cb - 1 - s;
    float v = (((unsigned)gr < HW) & ((unsigned)gc < HW))
            ? x[(size_t)ic*(HW*HW) + gr*HW + gc] : 0.f;
    xh[idx] = (_Float16)v;
}

// ---------- weight prep (fp16, K-permuted to match the packed build).
// Pair p occupies k-slots 2p,2p+1 holding original features FLO[p],FHI[p] (255=pad->0).
// Slab layout: elem = ((kc*2+hi))*1024 + oc*8 + i  (k = kc*16+hi*8+i), fp16.
__global__ __launch_bounds__(256) void prep_w2(const float* __restrict__ w,
                                               char* __restrict__ wh) {
    constexpr uint8_t FLO[32] = {0,2,4,6,8, 9,11,13,15,17, 26,19, 39,34, 48,45,
                                 28,21, 41,36, 30,23, 53,50, 43,32, 18,22, 255,255,255,255};
    constexpr uint8_t FHI[32] = {1,3,5,7,255, 10,12,14,16,255, 33,27, 44,40, 51,49,
                                 35,29, 46,42, 37,31, 52,47, 38,25, 20,24, 255,255,255,255};
    int idx = blockIdx.x*256 + threadIdx.x;   // 262144
    int p  = idx & 31;
    int oc = (idx >> 5) & 127;
    int c  = idx >> 12;
    int f0 = FLO[p], f1 = FHI[p];
    float v0 = (f0 != 255) ? w[(oc*CIN + c)*NF + f0] : 0.f;
    float v1 = (f1 != 255) ? w[(oc*CIN + c)*NF + f1] : 0.f;
    h2 pk; pk[0] = (_Float16)v0; pk[1] = (_Float16)v1;
    int elem = ((p>>3)*2 + ((p>>2)&1))*1024 + oc*8 + (p&3)*2;
    *(uint32_t*)(wh + (size_t)c*CHB + elem*2) = __builtin_bit_cast(uint32_t, pk);
}

template<int S>
__device__ __forceinline__ h2 bb(h2 q) { return __builtin_shufflevector(q, q, S, S); }
__device__ __forceinline__ h2 mk2(_Float16 a, _Float16 b) { h2 r; r[0]=a; r[1]=b; return r; }
__device__ __forceinline__ uint32_t bc(h2 x) { return __builtin_bit_cast(uint32_t, x); }

// Build lane's B-fragment for K-group KC from packed window regs Q0..Q4
// (Q0=(v0,v1) Q1=(v2,v3) Q2=(v4,v5) Q3=(v6,v7) Q4=(v8,1)). Each pr = one
// v_pk_mul_f16 (products born packed; no cvt/pack stage). hi-select = 4 cndmask.
template<int KC>
__device__ __forceinline__ f16x8 mkfragh(const h2 Q[5], int hi) {
    h2 pr0,pr1,pr2,pr3,pr4,pr5,pr6,pr7;
    if constexpr (KC==0) {
        pr0=Q[0]; pr1=Q[1]; pr2=Q[2]; pr3=Q[3]; pr4=Q[4];
        pr5=Q[0]*Q[0]; pr6=Q[1]*Q[1]; pr7=Q[2]*Q[2];
    } else if constexpr (KC==1) {
        pr0=Q[3]*Q[3];        pr1=Q[4]*Q[4];
        pr2=bb<0>(Q[0])*Q[1]; pr3=bb<1>(Q[0])*Q[1];
        pr4=bb<0>(Q[0])*Q[2]; pr5=bb<1>(Q[0])*Q[2];
        pr6=bb<0>(Q[0])*Q[3]; pr7=bb<1>(Q[0])*Q[3];
    } else if constexpr (KC==2) {
        pr0=bb<0>(Q[1])*Q[2]; pr1=bb<1>(Q[1])*Q[2];
        pr2=bb<0>(Q[1])*Q[3]; pr3=bb<1>(Q[1])*Q[3];
        pr4=bb<0>(Q[2])*Q[3]; pr5=bb<1>(Q[2])*Q[3];
        pr6=Q[0]*bb<0>(Q[4]); pr7=Q[1]*bb<0>(Q[4]);
    } else {
        pr0=Q[2]*bb<0>(Q[4]); pr1=Q[3]*bb<0>(Q[4]);
        pr2=mk2(Q[0][0],Q[1][0])*mk2(Q[0][1],Q[1][1]);   // (v0v1, v2v3)
        pr3=mk2(Q[2][0],Q[3][0])*mk2(Q[2][1],Q[3][1]);   // (v4v5, v6v7)
        pr4=Q[0]; pr5=Q[0]; pr6=Q[0]; pr7=Q[0];          // pads (weight 0)
    }
    union { uint32_t u[4]; f16x8 v; } t;
    t.u[0] = hi ? bc(pr4) : bc(pr0);
    t.u[1] = hi ? bc(pr5) : bc(pr1);
    t.u[2] = hi ? bc(pr6) : bc(pr2);
    t.u[3] = hi ? bc(pr7) : bc(pr3);
    return t.v;
}

__device__ __forceinline__ void gload_lds16(const void* g, void* l) {
    __builtin_amdgcn_global_load_lds(
        (const __attribute__((address_space(1))) void*)g,
        (__attribute__((address_space(3))) void*)l, 16, 0, 0);
}

// one K-group: 4 A ds_reads + packed build + 4 MFMA. KC/WSEL compile-time.
template<int KC, int WSEL>
__device__ __forceinline__ void kcsteph(const char* bufc, const h2* Q, int hi,
                                        int l31, f32x16 (&acc)[4]) {
    f16x8 A[4];
#pragma unroll
    for (int os = 0; os < 4; os++)
        A[os] = *(const f16x8*)(bufc + (KC*2 + hi)*2048 + (((os^WSEL)*32) + l31)*16);
    f16x8 tb = mkfragh<KC>(Q, hi);
#pragma unroll
    for (int os = 0; os < 4; os++)
        acc[os] = __builtin_amdgcn_mfma_f32_32x32x16_f16(A[os], tb, acc[os], 0, 0, 0);
}

// ---------- main (r13 structure, fp16 packed build). Block = 512 thr = 8 waves
// = 4 pos-groups x 2 channel-halves. Wave = 32 pos x 128 oc x 32 channels.
// Per-half LDS slab double-buffer, 1 barrier/channel. XOR oc-ownership
// (os ^ (h<<1)); K-combine with partner wave (wv^4). All acc indices static.
// mfma_f32_32x32x16_f16: A/B lane: row/col=lane&31, k=(lane>>5)*8+i;
// D: col=lane&31, row=(reg&3)+8*(reg>>2)+4*(lane>>5).
__global__ __launch_bounds__(512, 4) void socg_f16(const _Float16* __restrict__ xh,
                                                   const char* __restrict__ wh,
                                                   float* __restrict__ out) {
    __shared__ __align__(16) char sw[2][2][CHB];   // [half][dbuf][slab] = 64 KiB

    const int tid  = threadIdx.x;
    const int lane = tid & 63;
    const int wv   = tid >> 6;
    const int g    = wv & 3;
    const int h    = wv >> 2;
    const int hi   = lane >> 5;
    const int l31  = lane & 31;
    const int wsel = h << 1;

    const int bid  = blockIdx.x;    // 576 = 8 imgs * 72 tiles
    const int bimg = bid & 7;
    const int rem  = bid >> 3;
    const int h0   = (rem / 6) * 8;
    const int w0   = (rem % 6) * 16;

    const int r0 = h0 + g*2 + (l31 >> 4);
    const int c0 = w0 + (l31 & 15);
    const int sl = c0 & 1;          // parity copy -> 4B-aligned window loads

    // window rows r0-1..r0+1 = buffer rows r0..r0+2; col start = c0+sl (even)
    const char* xaddr = (const char*)xh + (size_t)sl*COPYB
        + 2*((size_t)(bimg*CIN + h*32)*CSLAB + (size_t)r0*PW2 + (c0 + sl));

    f32x16 acc[4];
#pragma unroll
    for (int os = 0; os < 4; os++)
#pragma unroll
        for (int r = 0; r < 16; r++) acc[os][r] = 0.f;

    // prologue: stage channel-0 slab for my half
    {
        const char* wsrc = wh + (size_t)(h*32)*CHB;
#pragma unroll
        for (int i = 0; i < 4; i++) {
            const int m = i*4 + g;
            gload_lds16(wsrc + m*1024 + lane*16, &sw[h][0][0] + m*1024);
        }
    }
    __syncthreads();

#pragma unroll 1
    for (int t = 0; t < 32; t++) {
        char* bufc = &sw[h][t & 1][0];
        // 1) window loads FIRST (their wait leaves staging in flight)
        const char* xc = xaddr + (size_t)t*(CSLAB*2);
        h2 L0 = *(const h2*)(xc);       h2 H0 = *(const h2*)(xc + 4);
        h2 L1 = *(const h2*)(xc + 196); h2 H1 = *(const h2*)(xc + 200);
        h2 L2 = *(const h2*)(xc + 392); h2 H2 = *(const h2*)(xc + 396);
        // 2) stage next channel's slab (drains at the end-of-step barrier)
        if (t + 1 < 32) {
            const char* wsrc = wh + (size_t)(h*32 + t + 1)*CHB;
            char* bufn = &sw[h][(t + 1) & 1][0];
#pragma unroll
            for (int i = 0; i < 4; i++) {
                const int m = i*4 + g;
                gload_lds16(wsrc + m*1024 + lane*16, bufn + m*1024);
            }
        }
        // 3) packed window regs: Q0=(v0,v1) Q1=(v2,v3) Q2=(v4,v5) Q3=(v6,v7) Q4=(v8,1)
        h2 Q[5];
        Q[0] = L0;
        Q[1] = mk2(H0[0], L1[0]);
        Q[2] = mk2(L1[1], H1[0]);
        Q[3] = L2;
        Q[4] = mk2(H2[0], (_Float16)1.0f);
        // 4) 4 K-groups
        if (h == 0) {
            kcsteph<0, 0>(bufc, Q, hi, l31, acc);
            kcsteph<1, 0>(bufc, Q, hi, l31, acc);
            kcsteph<2, 0>(bufc, Q, hi, l31, acc);
            kcsteph<3, 0>(bufc, Q, hi, l31, acc);
        } else {
            kcsteph<0, 2>(bufc, Q, hi, l31, acc);
            kcsteph<1, 2>(bufc, Q, hi, l31, acc);
            kcsteph<2, 2>(bufc, Q, hi, l31, acc);
            kcsteph<3, 2>(bufc, Q, hi, l31, acc);
        }
        // 5) barrier: slab reads done + stage(t+1) landed
        __syncthreads();
    }

    // ---- K-combine with partner wave (wv^4): store local acc[2],acc[3]
    // (partner's oc blocks), add partner's into acc[0],acc[1]. Static indices.
    {
        char* lred = &sw[0][0][0];
        char* my = lred + wv*8192;
#pragma unroll
        for (int g2 = 0; g2 < 8; g2++) {
            f32x4 v;
            v[0] = acc[2 + (g2>>2)][(g2&3)*4 + 0];
            v[1] = acc[2 + (g2>>2)][(g2&3)*4 + 1];
            v[2] = acc[2 + (g2>>2)][(g2&3)*4 + 2];
            v[3] = acc[2 + (g2>>2)][(g2&3)*4 + 3];
            *(f32x4*)(my + g2*1024 + lane*16) = v;
        }
        __syncthreads();
        const char* ot = lred + (wv ^ 4)*8192;
#pragma unroll
        for (int g2 = 0; g2 < 8; g2++) {
            f32x4 v = *(const f32x4*)(ot + g2*1024 + lane*16);
            acc[g2>>2][(g2&3)*4 + 0] += v[0];
            acc[g2>>2][(g2&3)*4 + 1] += v[1];
            acc[g2>>2][(g2&3)*4 + 2] += v[2];
            acc[g2>>2][(g2&3)*4 + 3] += v[3];
        }
    }

    const size_t obase = (size_t)bimg*OCH*HW*HW + (size_t)r0*HW + c0;
#pragma unroll
    for (int osl = 0; osl < 2; osl++) {
        const int gblk = osl ^ wsel;
#pragma unroll
        for (int r = 0; r < 16; r++) {
            const int oc = gblk*32 + (r & 3) + 8*(r >> 2) + 4*hi;
            out[obase + (size_t)oc*(HW*HW)] = acc[osl][r];
        }
    }
}

// ================= fallback path (ws too small): r13-era bf16 kernel =========
#define PCH (HW*HW)
__device__ __forceinline__ constexpr int PIc(int k) {
    constexpr int t[36] = {0,1,2,3,4,5,6,7, 0,1,2,3,4,5,6, 0,1,2,3,4,5,
                           0,1,2,3,4, 0,1,2,3, 0,1,2, 0,1, 0};
    return t[k];
}
__device__ __forceinline__ constexpr int PJc(int k) {
    constexpr int t[36] = {1,2,3,4,5,6,7,8, 2,3,4,5,6,7,8, 3,4,5,6,7,8,
                           4,5,6,7,8, 5,6,7,8, 6,7,8, 7,8, 8};
    return t[k];
}
__device__ __forceinline__ float featv(int k, const float* q) {
    return (k < 9)  ? q[k]
         : (k < 18) ? q[k-9] * q[k-9]
         : (k < 54) ? q[PIc(k-18)] * q[PJc(k-18)]
         : 0.f;
}
template<int KC>
__device__ __forceinline__ bf16x8 mkfrag(const float* q, int hi) {
    uint32_t P[8];
#pragma unroll
    for (int j = 0; j < 8; j++) {
        union { __bf16 b[2]; uint32_t u; } pk;
        pk.b[0] = (__bf16)featv(KC*16 + 2*j,     q);
        pk.b[1] = (__bf16)featv(KC*16 + 2*j + 1, q);
        P[j] = pk.u;
    }
    union { uint32_t u[4]; bf16x8 v; } t;
#pragma unroll
    for (int j = 0; j < 4; j++) t.u[j] = hi ? P[4+j] : P[j];
    return t.v;
}
__global__ __launch_bounds__(256) void prep_w(const float* __restrict__ w,
                                              __bf16* __restrict__ wb) {
    int idx = blockIdx.x * 256 + threadIdx.x;
    int j  = idx & 31;
    int oc = (idx >> 5) & 127;
    int c  = idx >> 12;
    int k  = 2 * j;
    int kc = k >> 4, hi = (k >> 3) & 1, i = k & 7;
    float v0 = (k     < NF) ? w[(oc*CIN + c)*NF + k    ] : 0.f;
    float v1 = (k + 1 < NF) ? w[(oc*CIN + c)*NF + k + 1] : 0.f;
    size_t off = ((size_t)(c*8 + kc*2 + hi))*1024 + oc*8 + i;
    union { __bf16 b[2]; uint32_t u; } pk;
    pk.b[0] = (__bf16)v0; pk.b[1] = (__bf16)v1;
    *(uint32_t*)((char*)wb + off*2) = pk.u;
}
template<int KC, int WSEL>
__device__ __forceinline__ void kcstep_g(const __bf16* wc_, const float* q, int hi,
                                         int l31, f32x16 (&acc)[4]) {
    bf16x8 A[4];
#pragma unroll
    for (int os = 0; os < 4; os++)
        A[os] = *(const bf16x8*)(wc_ + (KC*2 + hi)*1024 + (((os^WSEL)*32) + l31)*8);
    bf16x8 tb = mkfrag<KC>(q, hi);
#pragma unroll
    for (int os = 0; os < 4; os++)
        acc[os] = __builtin_amdgcn_mfma_f32_32x32x16_bf16(A[os], tb, acc[os], 0, 0, 0);
}
__global__ __launch_bounds__(64, 3) void socg_fb(const float* __restrict__ x,
                                                 const __bf16* __restrict__ wb,
                                                 float* __restrict__ out) {
    const int lane = threadIdx.x;
    const int hi   = lane >> 5;
    const int l31  = lane & 31;
    const int bid  = blockIdx.x;
    const int bimg = bid / 288;
    const int rem  = bid - bimg * 288;
    const int h0   = (rem / 6) * 2;
    const int w0   = (rem % 6) * 16;
    const int hA = h0 + (l31 >> 4);
    const int wA = w0 + (l31 & 15);
    int off[9]; float msk[9];
#pragma unroll
    for (int rr = 0; rr < 3; rr++)
#pragma unroll
        for (int cc = 0; cc < 3; cc++) {
            int hh = hA - 1 + rr, ww = wA - 1 + cc;
            bool ok = ((unsigned)hh < HW) && ((unsigned)ww < HW);
            int hc = hh < 0 ? 0 : (hh > HW-1 ? HW-1 : hh);
            int wc = ww < 0 ? 0 : (ww > HW-1 ? HW-1 : ww);
            off[rr*3 + cc] = hc * HW + wc;
            msk[rr*3 + cc] = ok ? 1.f : 0.f;
        }
    const float* xb = x + (size_t)bimg * CIN * PCH;
    f32x16 acc[4];
#pragma unroll
    for (int os = 0; os < 4; os++)
#pragma unroll
        for (int r = 0; r < 16; r++) acc[os][r] = 0.f;
    float rA[9], rB[9];
#pragma unroll
    for (int i = 0; i < 9; i++) rA[i] = xb[off[i]];
    auto body = [&](float (&rc)[9], float (&rn)[9], int c) {
        const __bf16* wc_ = wb + (size_t)c * 8192;
        if (c + 1 < CIN) {
            const float* xn = xb + (size_t)(c + 1) * PCH;
#pragma unroll
            for (int i = 0; i < 9; i++) rn[i] = xn[off[i]];
        }
        float q[9];
#pragma unroll
        for (int i = 0; i < 9; i++) q[i] = rc[i] * msk[i];
        kcstep_g<0, 0>(wc_, q, hi, l31, acc);
        kcstep_g<1, 0>(wc_, q, hi, l31, acc);
        kcstep_g<2, 0>(wc_, q, hi, l31, acc);
        kcstep_g<3, 0>(wc_, q, hi, l31, acc);
    };
#pragma unroll 1
    for (int c2 = 0; c2 < CIN; c2 += 2) {
        body(rA, rB, c2);
        body(rB, rA, c2 + 1);
    }
#pragma unroll
    for (int os = 0; os < 4; os++)
#pragma unroll
        for (int r = 0; r < 16; r++) {
            int oc = os*32 + (r & 3) + 8*(r >> 2) + 4*hi;
            out[(((size_t)bimg*OCH + oc)*HW + hA)*HW + wA] = acc[os][r];
        }
}

extern "C" void kernel_launch(void* const* d_in, const int* in_sizes, int n_in,
                              void* d_out, int out_size, void* d_ws, size_t ws_size,
                              hipStream_t stream) {
    const float* x = (const float*)d_in[0];
    const float* w = (const float*)d_in[1];
    float* out = (float*)d_out;
    if (ws_size >= XH_BYTES + WB_BYTES) {
        _Float16* xh = (_Float16*)d_ws;
        char* wh = (char*)d_ws + XH_BYTES;
        hipLaunchKernelGGL(prep_pad2, dim3((unsigned)((XH_BYTES/2)/256)), dim3(256), 0, stream, x, xh);
        hipLaunchKernelGGL(prep_w2, dim3(1024), dim3(256), 0, stream, w, wh);
        hipLaunchKernelGGL(socg_f16, dim3(576), dim3(512), 0, stream, xh, wh, out);
    } else {
        __bf16* wbf = (__bf16*)d_ws;
        hipLaunchKernelGGL(prep_w, dim3(1024), dim3(256), 0, stream, w, wbf);
        hipLaunchKernelGGL(socg_fb, dim3(2304), dim3(64), 0, stream, x, wbf, out);
    }
}

// Round 18
// 122.291 us; speedup vs baseline: 1.7986x; 1.1095x over previous
//
#include <hip/hip_runtime.h>
#include <hip/hip_bf16.h>
#include <stdint.h>

typedef __attribute__((ext_vector_type(16))) float f32x16;
typedef __attribute__((ext_vector_type(4)))  float f32x4;
typedef __attribute__((ext_vector_type(8)))  __bf16 bf16x8;
typedef _Float16 h2    __attribute__((ext_vector_type(2)));   // packed fp16 pair (1 VGPR)
typedef _Float16 f16x8 __attribute__((ext_vector_type(8)));   // MFMA A/B operand

#define CIN 64
#define HW 96
#define OCH 128
#define NF 54
#define PW2 98
#define CSLAB (PW2*PW2)                  // 9604 elems per channel (fp16 padded)
#define COPYE ((size_t)8*CIN*CSLAB)      // 4,917,248 elems per parity copy
#define COPYB (COPYE*2)                  // bytes per copy
#define XH_BYTES (COPYB*2)               // 19,668,992
#define CHB 16384                        // per-channel weight slab bytes (128oc x 64k x 2B)
#define WB_BYTES ((size_t)CIN*CHB)       // 1 MiB

// ---------- input prep: fp32 [8][64][96][96] -> TWO fp16 padded copies
// copy s: buffer col cb <-> global col cb-1-s; row rb <-> global row rb-1.
// Lane with position col c0 uses copy s=c0&1 so its window byte addr is 4B-aligned.
__global__ __launch_bounds__(256) void prep_pad2(const float* __restrict__ x,
                                                 _Float16* __restrict__ xh) {
    size_t idx = (size_t)blockIdx.x*256 + threadIdx.x;   // 9,834,496 total
    int s  = (int)(idx / COPYE);
    int r1 = (int)(idx - (size_t)s*COPYE);
    int ic = r1 / CSLAB;
    int r2 = r1 - ic*CSLAB;
    int rb = r2 / PW2, cb = r2 - rb*PW2;
    int gr = rb - 1, gc = cb - 1 - s;
    float v = (((unsigned)gr < HW) & ((unsigned)gc < HW))
            ? x[(size_t)ic*(HW*HW) + gr*HW + gc] : 0.f;
    xh[idx] = (_Float16)v;
}

// ---------- weight prep (fp16, K-permuted to match the packed build).
// Pair p occupies k-slots 2p,2p+1 holding original features FLO[p],FHI[p] (255=pad->0).
// Slab layout: elem = ((kc*2+hi))*1024 + oc*8 + i  (k = kc*16+hi*8+i), fp16.
__global__ __launch_bounds__(256) void prep_w2(const float* __restrict__ w,
                                               char* __restrict__ wh) {
    constexpr uint8_t FLO[32] = {0,2,4,6,8, 9,11,13,15,17, 26,19, 39,34, 48,45,
                                 28,21, 41,36, 30,23, 53,50, 43,32, 18,22, 255,255,255,255};
    constexpr uint8_t FHI[32] = {1,3,5,7,255, 10,12,14,16,255, 33,27, 44,40, 51,49,
                                 35,29, 46,42, 37,31, 52,47, 38,25, 20,24, 255,255,255,255};
    int idx = blockIdx.x*256 + threadIdx.x;   // 262144
    int p  = idx & 31;
    int oc = (idx >> 5) & 127;
    int c  = idx >> 12;
    int f0 = FLO[p], f1 = FHI[p];
    float v0 = (f0 != 255) ? w[(oc*CIN + c)*NF + f0] : 0.f;
    float v1 = (f1 != 255) ? w[(oc*CIN + c)*NF + f1] : 0.f;
    h2 pk; pk[0] = (_Float16)v0; pk[1] = (_Float16)v1;
    int elem = ((p>>3)*2 + ((p>>2)&1))*1024 + oc*8 + (p&3)*2;
    *(uint32_t*)(wh + (size_t)c*CHB + elem*2) = __builtin_bit_cast(uint32_t, pk);
}

template<int S>
__device__ __forceinline__ h2 bb(h2 q) { return __builtin_shufflevector(q, q, S, S); }
__device__ __forceinline__ h2 mk2(_Float16 a, _Float16 b) { h2 r; r[0]=a; r[1]=b; return r; }
__device__ __forceinline__ uint32_t bc(h2 x) { return __builtin_bit_cast(uint32_t, x); }

// Build lane's B-fragment for K-group KC from packed window regs Q0..Q4
// (Q0=(v0,v1) Q1=(v2,v3) Q2=(v4,v5) Q3=(v6,v7) Q4=(v8,1)). Each pr = one
// v_pk_mul_f16 (products born packed; no cvt/pack stage). hi-select = 4 cndmask.
template<int KC>
__device__ __forceinline__ f16x8 mkfragh(const h2 Q[5], int hi) {
    h2 pr0,pr1,pr2,pr3,pr4,pr5,pr6,pr7;
    if constexpr (KC==0) {
        pr0=Q[0]; pr1=Q[1]; pr2=Q[2]; pr3=Q[3]; pr4=Q[4];
        pr5=Q[0]*Q[0]; pr6=Q[1]*Q[1]; pr7=Q[2]*Q[2];
    } else if constexpr (KC==1) {
        pr0=Q[3]*Q[3];        pr1=Q[4]*Q[4];
        pr2=bb<0>(Q[0])*Q[1]; pr3=bb<1>(Q[0])*Q[1];
        pr4=bb<0>(Q[0])*Q[2]; pr5=bb<1>(Q[0])*Q[2];
        pr6=bb<0>(Q[0])*Q[3]; pr7=bb<1>(Q[0])*Q[3];
    } else if constexpr (KC==2) {
        pr0=bb<0>(Q[1])*Q[2]; pr1=bb<1>(Q[1])*Q[2];
        pr2=bb<0>(Q[1])*Q[3]; pr3=bb<1>(Q[1])*Q[3];
        pr4=bb<0>(Q[2])*Q[3]; pr5=bb<1>(Q[2])*Q[3];
        pr6=Q[0]*bb<0>(Q[4]); pr7=Q[1]*bb<0>(Q[4]);
    } else {
        pr0=Q[2]*bb<0>(Q[4]); pr1=Q[3]*bb<0>(Q[4]);
        pr2=mk2(Q[0][0],Q[1][0])*mk2(Q[0][1],Q[1][1]);   // (v0v1, v2v3)
        pr3=mk2(Q[2][0],Q[3][0])*mk2(Q[2][1],Q[3][1]);   // (v4v5, v6v7)
        pr4=Q[0]; pr5=Q[0]; pr6=Q[0]; pr7=Q[0];          // pads (weight 0)
    }
    union { uint32_t u[4]; f16x8 v; } t;
    t.u[0] = hi ? bc(pr4) : bc(pr0);
    t.u[1] = hi ? bc(pr5) : bc(pr1);
    t.u[2] = hi ? bc(pr6) : bc(pr2);
    t.u[3] = hi ? bc(pr7) : bc(pr3);
    return t.v;
}

__device__ __forceinline__ void gload_lds16(const void* g, void* l) {
    __builtin_amdgcn_global_load_lds(
        (const __attribute__((address_space(1))) void*)g,
        (__attribute__((address_space(3))) void*)l, 16, 0, 0);
}

// one K-group: 4 A ds_reads + packed build + 4 MFMA. KC/WSEL compile-time.
template<int KC, int WSEL>
__device__ __forceinline__ void kcsteph(const char* bufc, const h2* Q, int hi,
                                        int l31, f32x16 (&acc)[4]) {
    f16x8 A[4];
#pragma unroll
    for (int os = 0; os < 4; os++)
        A[os] = *(const f16x8*)(bufc + (KC*2 + hi)*2048 + (((os^WSEL)*32) + l31)*16);
    f16x8 tb = mkfragh<KC>(Q, hi);
#pragma unroll
    for (int os = 0; os < 4; os++)
        acc[os] = __builtin_amdgcn_mfma_f32_32x32x16_f16(A[os], tb, acc[os], 0, 0, 0);
}

// ---------- main (r17 + window DOUBLE-BUFFER prefetch). Block = 512 thr =
// 8 waves = 4 pos-groups x 2 channel-halves. Wave = 32 pos x 128 oc x 32
// channels. Per-half LDS slab dbuf, 1 barrier/channel. The window for channel
// t+1 is issued DURING step t, BEFORE the staging gload_lds: in-order vmcnt
// means next step's Q-build waits at a counted vmcnt (staging stays in
// flight), and the Q-build at step start reads already-resident registers —
// removes the ~400-cyc L2 round-trip that headed every step in r17.
// XOR oc-ownership (os ^ (h<<1)); K-combine with partner wave (wv^4).
// All acc indices compile-time (rule #20).
// mfma_f32_32x32x16_f16: A/B lane: row/col=lane&31, k=(lane>>5)*8+i;
// D: col=lane&31, row=(reg&3)+8*(reg>>2)+4*(lane>>5).
__global__ __launch_bounds__(512, 4) void socg_f16(const _Float16* __restrict__ xh,
                                                   const char* __restrict__ wh,
                                                   float* __restrict__ out) {
    __shared__ __align__(16) char sw[2][2][CHB];   // [half][dbuf][slab] = 64 KiB

    const int tid  = threadIdx.x;
    const int lane = tid & 63;
    const int wv   = tid >> 6;
    const int g    = wv & 3;
    const int h    = wv >> 2;
    const int hi   = lane >> 5;
    const int l31  = lane & 31;
    const int wsel = h << 1;

    const int bid  = blockIdx.x;    // 576 = 8 imgs * 72 tiles
    const int bimg = bid & 7;
    const int rem  = bid >> 3;
    const int h0   = (rem / 6) * 8;
    const int w0   = (rem % 6) * 16;

    const int r0 = h0 + g*2 + (l31 >> 4);
    const int c0 = w0 + (l31 & 15);
    const int sl = c0 & 1;          // parity copy -> 4B-aligned window loads

    // window rows r0-1..r0+1 = buffer rows r0..r0+2; col start = c0+sl (even)
    const char* xaddr = (const char*)xh + (size_t)sl*COPYB
        + 2*((size_t)(bimg*CIN + h*32)*CSLAB + (size_t)r0*PW2 + (c0 + sl));

    f32x16 acc[4];
#pragma unroll
    for (int os = 0; os < 4; os++)
#pragma unroll
        for (int r = 0; r < 16; r++) acc[os][r] = 0.f;

    // prologue: stage channel-0 slab for my half + load channel-0 window
    {
        const char* wsrc = wh + (size_t)(h*32)*CHB;
#pragma unroll
        for (int i = 0; i < 4; i++) {
            const int m = i*4 + g;
            gload_lds16(wsrc + m*1024 + lane*16, &sw[h][0][0] + m*1024);
        }
    }
    h2 WA[6], WB[6];    // window dbuf: [L0,H0,L1,H1,L2,H2]
    {
        const char* xc = xaddr;
        WA[0] = *(const h2*)(xc);       WA[1] = *(const h2*)(xc + 4);
        WA[2] = *(const h2*)(xc + 196); WA[3] = *(const h2*)(xc + 200);
        WA[4] = *(const h2*)(xc + 392); WA[5] = *(const h2*)(xc + 396);
    }
    __syncthreads();

    auto body = [&](h2 (&Wc)[6], h2 (&Wn)[6], int t) {
        char* bufc = &sw[h][t & 1][0];
        // 1) prefetch NEXT channel's window FIRST (so its vmcnt position is
        //    before staging), then stage next slab.
        if (t + 1 < 32) {
            const char* xn = xaddr + (size_t)(t + 1)*(CSLAB*2);
            Wn[0] = *(const h2*)(xn);       Wn[1] = *(const h2*)(xn + 4);
            Wn[2] = *(const h2*)(xn + 196); Wn[3] = *(const h2*)(xn + 200);
            Wn[4] = *(const h2*)(xn + 392); Wn[5] = *(const h2*)(xn + 396);
            const char* wsrc = wh + (size_t)(h*32 + t + 1)*CHB;
            char* bufn = &sw[h][(t + 1) & 1][0];
#pragma unroll
            for (int i = 0; i < 4; i++) {
                const int m = i*4 + g;
                gload_lds16(wsrc + m*1024 + lane*16, bufn + m*1024);
            }
        }
        // 2) packed window regs from RESIDENT prefetched regs:
        //    Q0=(v0,v1) Q1=(v2,v3) Q2=(v4,v5) Q3=(v6,v7) Q4=(v8,1)
        h2 Q[5];
        Q[0] = Wc[0];
        Q[1] = mk2(Wc[1][0], Wc[2][0]);
        Q[2] = mk2(Wc[2][1], Wc[3][0]);
        Q[3] = Wc[4];
        Q[4] = mk2(Wc[5][0], (_Float16)1.0f);
        // 3) 4 K-groups
        if (h == 0) {
            kcsteph<0, 0>(bufc, Q, hi, l31, acc);
            kcsteph<1, 0>(bufc, Q, hi, l31, acc);
            kcsteph<2, 0>(bufc, Q, hi, l31, acc);
            kcsteph<3, 0>(bufc, Q, hi, l31, acc);
        } else {
            kcsteph<0, 2>(bufc, Q, hi, l31, acc);
            kcsteph<1, 2>(bufc, Q, hi, l31, acc);
            kcsteph<2, 2>(bufc, Q, hi, l31, acc);
            kcsteph<3, 2>(bufc, Q, hi, l31, acc);
        }
        // 4) barrier: slab reads done + stage(t+1) landed
        __syncthreads();
    };

#pragma unroll 1
    for (int t2 = 0; t2 < 32; t2 += 2) {
        body(WA, WB, t2);
        body(WB, WA, t2 + 1);
    }

    // ---- K-combine with partner wave (wv^4): store local acc[2],acc[3]
    // (partner's oc blocks), add partner's into acc[0],acc[1]. Static indices.
    {
        char* lred = &sw[0][0][0];
        char* my = lred + wv*8192;
#pragma unroll
        for (int g2 = 0; g2 < 8; g2++) {
            f32x4 v;
            v[0] = acc[2 + (g2>>2)][(g2&3)*4 + 0];
            v[1] = acc[2 + (g2>>2)][(g2&3)*4 + 1];
            v[2] = acc[2 + (g2>>2)][(g2&3)*4 + 2];
            v[3] = acc[2 + (g2>>2)][(g2&3)*4 + 3];
            *(f32x4*)(my + g2*1024 + lane*16) = v;
        }
        __syncthreads();
        const char* ot = lred + (wv ^ 4)*8192;
#pragma unroll
        for (int g2 = 0; g2 < 8; g2++) {
            f32x4 v = *(const f32x4*)(ot + g2*1024 + lane*16);
            acc[g2>>2][(g2&3)*4 + 0] += v[0];
            acc[g2>>2][(g2&3)*4 + 1] += v[1];
            acc[g2>>2][(g2&3)*4 + 2] += v[2];
            acc[g2>>2][(g2&3)*4 + 3] += v[3];
        }
    }

    const size_t obase = (size_t)bimg*OCH*HW*HW + (size_t)r0*HW + c0;
#pragma unroll
    for (int osl = 0; osl < 2; osl++) {
        const int gblk = osl ^ wsel;
#pragma unroll
        for (int r = 0; r < 16; r++) {
            const int oc = gblk*32 + (r & 3) + 8*(r >> 2) + 4*hi;
            out[obase + (size_t)oc*(HW*HW)] = acc[osl][r];
        }
    }
}

// ================= fallback path (ws too small): bf16 register kernel =========
#define PCH (HW*HW)
__device__ __forceinline__ constexpr int PIc(int k) {
    constexpr int t[36] = {0,1,2,3,4,5,6,7, 0,1,2,3,4,5,6, 0,1,2,3,4,5,
                           0,1,2,3,4, 0,1,2,3, 0,1,2, 0,1, 0};
    return t[k];
}
__device__ __forceinline__ constexpr int PJc(int k) {
    constexpr int t[36] = {1,2,3,4,5,6,7,8, 2,3,4,5,6,7,8, 3,4,5,6,7,8,
                           4,5,6,7,8, 5,6,7,8, 6,7,8, 7,8, 8};
    return t[k];
}
__device__ __forceinline__ float featv(int k, const float* q) {
    return (k < 9)  ? q[k]
         : (k < 18) ? q[k-9] * q[k-9]
         : (k < 54) ? q[PIc(k-18)] * q[PJc(k-18)]
         : 0.f;
}
template<int KC>
__device__ __forceinline__ bf16x8 mkfrag(const float* q, int hi) {
    uint32_t P[8];
#pragma unroll
    for (int j = 0; j < 8; j++) {
        union { __bf16 b[2]; uint32_t u; } pk;
        pk.b[0] = (__bf16)featv(KC*16 + 2*j,     q);
        pk.b[1] = (__bf16)featv(KC*16 + 2*j + 1, q);
        P[j] = pk.u;
    }
    union { uint32_t u[4]; bf16x8 v; } t;
#pragma unroll
    for (int j = 0; j < 4; j++) t.u[j] = hi ? P[4+j] : P[j];
    return t.v;
}
__global__ __launch_bounds__(256) void prep_w(const float* __restrict__ w,
                                              __bf16* __restrict__ wb) {
    int idx = blockIdx.x * 256 + threadIdx.x;
    int j  = idx & 31;
    int oc = (idx >> 5) & 127;
    int c  = idx >> 12;
    int k  = 2 * j;
    int kc = k >> 4, hi = (k >> 3) & 1, i = k & 7;
    float v0 = (k     < NF) ? w[(oc*CIN + c)*NF + k    ] : 0.f;
    float v1 = (k + 1 < NF) ? w[(oc*CIN + c)*NF + k + 1] : 0.f;
    size_t off = ((size_t)(c*8 + kc*2 + hi))*1024 + oc*8 + i;
    union { __bf16 b[2]; uint32_t u; } pk;
    pk.b[0] = (__bf16)v0; pk.b[1] = (__bf16)v1;
    *(uint32_t*)((char*)wb + off*2) = pk.u;
}
template<int KC, int WSEL>
__device__ __forceinline__ void kcstep_g(const __bf16* wc_, const float* q, int hi,
                                         int l31, f32x16 (&acc)[4]) {
    bf16x8 A[4];
#pragma unroll
    for (int os = 0; os < 4; os++)
        A[os] = *(const bf16x8*)(wc_ + (KC*2 + hi)*1024 + (((os^WSEL)*32) + l31)*8);
    bf16x8 tb = mkfrag<KC>(q, hi);
#pragma unroll
    for (int os = 0; os < 4; os++)
        acc[os] = __builtin_amdgcn_mfma_f32_32x32x16_bf16(A[os], tb, acc[os], 0, 0, 0);
}
__global__ __launch_bounds__(64, 3) void socg_fb(const float* __restrict__ x,
                                                 const __bf16* __restrict__ wb,
                                                 float* __restrict__ out) {
    const int lane = threadIdx.x;
    const int hi   = lane >> 5;
    const int l31  = lane & 31;
    const int bid  = blockIdx.x;
    const int bimg = bid / 288;
    const int rem  = bid - bimg * 288;
    const int h0   = (rem / 6) * 2;
    const int w0   = (rem % 6) * 16;
    const int hA = h0 + (l31 >> 4);
    const int wA = w0 + (l31 & 15);
    int off[9]; float msk[9];
#pragma unroll
    for (int rr = 0; rr < 3; rr++)
#pragma unroll
        for (int cc = 0; cc < 3; cc++) {
            int hh = hA - 1 + rr, ww = wA - 1 + cc;
            bool ok = ((unsigned)hh < HW) && ((unsigned)ww < HW);
            int hc = hh < 0 ? 0 : (hh > HW-1 ? HW-1 : hh);
            int wc = ww < 0 ? 0 : (ww > HW-1 ? HW-1 : ww);
            off[rr*3 + cc] = hc * HW + wc;
            msk[rr*3 + cc] = ok ? 1.f : 0.f;
        }
    const float* xb = x + (size_t)bimg * CIN * PCH;
    f32x16 acc[4];
#pragma unroll
    for (int os = 0; os < 4; os++)
#pragma unroll
        for (int r = 0; r < 16; r++) acc[os][r] = 0.f;
    float rA[9], rB[9];
#pragma unroll
    for (int i = 0; i < 9; i++) rA[i] = xb[off[i]];
    auto body = [&](float (&rc)[9], float (&rn)[9], int c) {
        const __bf16* wc_ = wb + (size_t)c * 8192;
        if (c + 1 < CIN) {
            const float* xn = xb + (size_t)(c + 1) * PCH;
#pragma unroll
            for (int i = 0; i < 9; i++) rn[i] = xn[off[i]];
        }
        float q[9];
#pragma unroll
        for (int i = 0; i < 9; i++) q[i] = rc[i] * msk[i];
        kcstep_g<0, 0>(wc_, q, hi, l31, acc);
        kcstep_g<1, 0>(wc_, q, hi, l31, acc);
        kcstep_g<2, 0>(wc_, q, hi, l31, acc);
        kcstep_g<3, 0>(wc_, q, hi, l31, acc);
    };
#pragma unroll 1
    for (int c2 = 0; c2 < CIN; c2 += 2) {
        body(rA, rB, c2);
        body(rB, rA, c2 + 1);
    }
#pragma unroll
    for (int os = 0; os < 4; os++)
#pragma unroll
        for (int r = 0; r < 16; r++) {
            int oc = os*32 + (r & 3) + 8*(r >> 2) + 4*hi;
            out[(((size_t)bimg*OCH + oc)*HW + hA)*HW + wA] = acc[os][r];
        }
}

extern "C" void kernel_launch(void* const* d_in, const int* in_sizes, int n_in,
                              void* d_out, int out_size, void* d_ws, size_t ws_size,
                              hipStream_t stream) {
    const float* x = (const float*)d_in[0];
    const float* w = (const float*)d_in[1];
    float* out = (float*)d_out;
    if (ws_size >= XH_BYTES + WB_BYTES) {
        _Float16* xh = (_Float16*)d_ws;
        char* wh = (char*)d_ws + XH_BYTES;
        hipLaunchKernelGGL(prep_pad2, dim3((unsigned)((XH_BYTES/2)/256)), dim3(256), 0, stream, x, xh);
        hipLaunchKernelGGL(prep_w2, dim3(1024), dim3(256), 0, stream, w, wh);
        hipLaunchKernelGGL(socg_f16, dim3(576), dim3(512), 0, stream, xh, wh, out);
    } else {
        __bf16* wbf = (__bf16*)d_ws;
        hipLaunchKernelGGL(prep_w, dim3(1024), dim3(256), 0, stream, w, wbf);
        hipLaunchKernelGGL(socg_fb, dim3(2304), dim3(64), 0, stream, x, wbf, out);
    }
}